// Round 3
// baseline (1306.951 us; speedup 1.0000x reference)
//
#include <hip/hip_runtime.h>

#define TPB 256

// ---- mean-VFE: x[n,c] = sum_p voxels[n,p,c] / max(nump[n],1), p=0..4, c=0..3
__global__ void vfe_kernel(const float* __restrict__ voxels,
                           const int* __restrict__ nump,
                           float* __restrict__ x, int N) {
    int i = blockIdx.x * blockDim.x + threadIdx.x;
    if (i >= N * 4) return;
    int n = i >> 2, c = i & 3;
    const float* v = voxels + (long)n * 20 + c;
    float s = v[0] + v[4] + v[8] + v[12] + v[16];
    x[i] = s / fmaxf((float)nump[n], 1.0f);
}

// ---- invert rulebook: inv[out_row][k] = in_row (or -1)
__global__ void inv_build_kernel(const int* __restrict__ rb_in,
                                 const int* __restrict__ rb_out,
                                 int* __restrict__ inv,
                                 int KP, int P, int K, int n_in) {
    int t = blockIdx.x * blockDim.x + threadIdx.x;
    if (t >= KP) return;
    int ii = rb_in[t];
    if (ii == n_in) return;                 // padded sentinel
    int k = t / P;
    inv[(long)rb_out[t] * K + k] = ii;
}

// ---- separate fused BN+ReLU (for the atomic K-split path)
__global__ void bnrelu_kernel(float* __restrict__ x,
                              const float* __restrict__ bn,
                              long total, int co) {
    long t = (long)blockIdx.x * blockDim.x + threadIdx.x;
    if (t >= total) return;
    int o = (int)(t % co);
    float g = bn[o], b = bn[co + o], m = bn[2 * co + o], v = bn[3 * co + o];
    float y = (x[t] - m) * rsqrtf(v + 1e-3f) * g + b;
    x[t] = fmaxf(y, 0.f);
}

// ---- output-centric sparse conv, software-pipelined (double-buffered LDS).
// ATOMIC=false: full K per block, fused BN+ReLU, plain stores.
// ATOMIC=true : taps [blockIdx.y*kpb, +kpb) per block, fp32 atomicAdd partials.
template<int CI, int CO, int TP, int K, bool DB, bool ATOMIC>
__global__ __launch_bounds__(256)
void conv_kernel(const float* __restrict__ feats,
                 const float* __restrict__ w,    // [K][CI][CO]
                 const float* __restrict__ bn,   // [4][CO]
                 const int* __restrict__ inv,    // [n_out][K]
                 float* __restrict__ out,        // [n_out][CO]
                 int n_out, int kpb) {
    constexpr int OG  = CO / 4;             // float4 col groups
    constexpr int PTH = 256 / OG;           // row-threads
    constexpr int PT  = TP / PTH;           // rows per thread
    constexpr int CIP = CI + 4;             // padded LDS row stride
    constexpr int NB  = DB ? 2 : 1;
    constexpr int W4  = CI * CO / 4;        // float4 count of one W tap
    constexpr int WCH = (W4 + 255) / 256;   // W float4 per thread
    constexpr int TR  = CI / 4;             // float4 threads per A row
    constexpr int RPS = 256 / TR;           // A rows per sweep
    constexpr int ASW = (TP + RPS - 1) / RPS;

    __shared__ float sW[NB][CI * CO];
    __shared__ float sA[NB][TP * CIP];
    __shared__ int   sI[TP * K];

    const int brow = blockIdx.x * TP;
    const int t  = threadIdx.x;
    const int og = t % OG;
    const int pg = t / OG;

    int kbeg = 0, kend = K;
    if (ATOMIC) { kbeg = blockIdx.y * kpb; kend = min(K, kbeg + kpb); }

    // stage this block's inv slice (row-major [n][K] -> linear copy)
    {
        long base = (long)brow * K, lim = (long)n_out * K;
        for (int i = t; i < TP * K; i += 256)
            sI[i] = (base + i < lim) ? inv[base + i] : -1;
    }

    float4 wreg[WCH];
    float4 areg[ASW];

    auto load_regs = [&](int k) {
        const float4* src = (const float4*)(w + (long)k * CI * CO);
        #pragma unroll
        for (int c = 0; c < WCH; ++c) {
            int i = c * 256 + t;
            if (W4 >= 256 || i < W4) wreg[c] = src[i];
        }
        #pragma unroll
        for (int s = 0; s < ASW; ++s) {
            int r = s * RPS + t / TR;
            int c = (t % TR) * 4;
            float4 v = make_float4(0.f, 0.f, 0.f, 0.f);
            if (r < TP) {
                int idx = sI[r * K + k];
                if (idx >= 0) v = *(const float4*)(feats + (long)idx * CI + c);
            }
            areg[s] = v;
        }
    };
    auto store_lds = [&](int b) {
        #pragma unroll
        for (int c = 0; c < WCH; ++c) {
            int i = c * 256 + t;
            if (W4 >= 256 || i < W4) ((float4*)sW[b])[i] = wreg[c];
        }
        #pragma unroll
        for (int s = 0; s < ASW; ++s) {
            int r = s * RPS + t / TR;
            int c = (t % TR) * 4;
            if (r < TP) *(float4*)(&sA[b][r * CIP + c]) = areg[s];
        }
    };

    float acc[PT][4];
    #pragma unroll
    for (int i = 0; i < PT; ++i)
        acc[i][0] = acc[i][1] = acc[i][2] = acc[i][3] = 0.f;

    auto compute = [&](int b) {
        #pragma unroll 4
        for (int kk = 0; kk < CI; ++kk) {
            float4 wv = *(const float4*)(&sW[b][kk * CO + og * 4]);
            #pragma unroll
            for (int i = 0; i < PT; ++i) {
                float a = sA[b][(pg * PT + i) * CIP + kk];
                acc[i][0] = fmaf(a, wv.x, acc[i][0]);
                acc[i][1] = fmaf(a, wv.y, acc[i][1]);
                acc[i][2] = fmaf(a, wv.z, acc[i][2]);
                acc[i][3] = fmaf(a, wv.w, acc[i][3]);
            }
        }
    };

    __syncthreads();                         // sI ready
    if (DB) {
        int cur = 0;
        load_regs(kbeg);
        store_lds(0);
        for (int k = kbeg; k < kend; ++k) {
            __syncthreads();                 // buf[cur] staged for all waves
            if (k + 1 < kend) load_regs(k + 1);   // global loads in flight
            compute(cur);                         // ...hidden under compute
            if (k + 1 < kend) store_lds(cur ^ 1);
            cur ^= 1;
        }
    } else {
        for (int k = kbeg; k < kend; ++k) {
            __syncthreads();
            load_regs(k);
            store_lds(0);
            __syncthreads();
            compute(0);
        }
    }

    if (ATOMIC) {
        #pragma unroll
        for (int i = 0; i < PT; ++i) {
            int grow = brow + pg * PT + i;
            if (grow < n_out) {
                float* dst = out + (long)grow * CO + og * 4;
                atomicAdd(dst + 0, acc[i][0]);
                atomicAdd(dst + 1, acc[i][1]);
                atomicAdd(dst + 2, acc[i][2]);
                atomicAdd(dst + 3, acc[i][3]);
            }
        }
    } else {
        float4 g = *(const float4*)(bn + og * 4);
        float4 b = *(const float4*)(bn + CO + og * 4);
        float4 m = *(const float4*)(bn + 2 * CO + og * 4);
        float4 v = *(const float4*)(bn + 3 * CO + og * 4);
        float s0 = rsqrtf(v.x + 1e-3f) * g.x;
        float s1 = rsqrtf(v.y + 1e-3f) * g.y;
        float s2 = rsqrtf(v.z + 1e-3f) * g.z;
        float s3 = rsqrtf(v.w + 1e-3f) * g.w;
        #pragma unroll
        for (int i = 0; i < PT; ++i) {
            int grow = brow + pg * PT + i;
            if (grow < n_out) {
                float4 o;
                o.x = fmaxf(fmaf(acc[i][0] - m.x, s0, b.x), 0.f);
                o.y = fmaxf(fmaf(acc[i][1] - m.y, s1, b.y), 0.f);
                o.z = fmaxf(fmaf(acc[i][2] - m.z, s2, b.z), 0.f);
                o.w = fmaxf(fmaf(acc[i][3] - m.w, s3, b.w), 0.f);
                *(float4*)(out + (long)grow * CO + og * 4) = o;
            }
        }
    }
}

// ---- per-batch max pool: LDS accumulation, few global atomics
__global__ void segmax_kernel(const float* __restrict__ x,
                              const int* __restrict__ bidx,
                              float* __restrict__ out, int rows, int nb) {
    __shared__ float sM[8 * 128];
    for (int i = threadIdx.x; i < nb * 128; i += 256) sM[i] = 0.f;
    __syncthreads();
    int c = threadIdx.x & 127;
    int sub = threadIdx.x >> 7;              // 2 rows in flight per block
    for (int r = blockIdx.x * 2 + sub; r < rows; r += gridDim.x * 2) {
        float v = x[(long)r * 128 + c];
        int b = bidx[r];
        atomicMax((int*)&sM[b * 128 + c], __float_as_int(v));  // LDS atomic
    }
    __syncthreads();
    for (int i = threadIdx.x; i < nb * 128; i += 256)
        atomicMax((int*)out + i, __float_as_int(sM[i]));
}

extern "C" void kernel_launch(void* const* d_in, const int* in_sizes, int n_in,
                              void* d_out, int out_size, void* d_ws, size_t ws_size,
                              hipStream_t stream) {
    (void)n_in; (void)ws_size;
    const float* voxels = (const float*)d_in[24];
    const int*   nump   = (const int*)d_in[25];
    const int N  = in_sizes[25];
    const int n2 = in_sizes[30] / 27;   // SubM pad width == site count
    const int n3 = in_sizes[34] / 27;
    const int n4 = in_sizes[38] / 27;
    const int n5 = in_sizes[42];        // batch_idx length

    struct L { int wi, rb, K, ci, co, nin, nout, tp; };
    const L layers[12] = {
        {0,  26, 27,  4,  16, N,  N,  64},
        {1,  26, 27, 16,  16, N,  N,  64},
        {2,  28, 27, 16,  32, N,  n2, 64},
        {3,  30, 27, 32,  32, n2, n2, 64},
        {4,  30, 27, 32,  32, n2, n2, 64},
        {5,  32, 27, 32,  64, n2, n3, 32},
        {6,  34, 27, 64,  64, n3, n3, 32},
        {7,  34, 27, 64,  64, n3, n3, 32},
        {8,  36, 27, 64,  64, n3, n4, 32},
        {9,  38, 27, 64,  64, n4, n4, 32},
        {10, 38, 27, 64,  64, n4, n4, 32},
        {11, 40,  3, 64, 128, n4, n5, 32},
    };

    // workspace: inv | bufA | bufB
    size_t inv_elems = 0, feat_elems = (size_t)N * 4;
    for (int i = 0; i < 12; ++i) {
        size_t ie = (size_t)layers[i].nout * layers[i].K;
        size_t fe = (size_t)layers[i].nout * layers[i].co;
        if (ie > inv_elems)  inv_elems  = ie;
        if (fe > feat_elems) feat_elems = fe;
    }
    size_t inv_b  = (inv_elems  * sizeof(int)   + 255) & ~(size_t)255;
    size_t feat_b = (feat_elems * sizeof(float) + 255) & ~(size_t)255;
    int*   inv  = (int*)d_ws;
    float* bufA = (float*)((char*)d_ws + inv_b);
    float* bufB = (float*)((char*)d_ws + inv_b + feat_b);

    {   // VFE
        long tot = (long)N * 4;
        vfe_kernel<<<dim3((unsigned)((tot + TPB - 1) / TPB)), dim3(TPB), 0, stream>>>(
            voxels, nump, bufA, N);
    }

    float* cur = bufA;
    float* nxt = bufB;
    int prev_rb = -1;
    for (int i = 0; i < 12; ++i) {
        const L& l = layers[i];
        const float* w  = (const float*)d_in[2 * l.wi];
        const float* bn = (const float*)d_in[2 * l.wi + 1];

        if (l.rb != prev_rb) {
            const int* rin  = (const int*)d_in[l.rb];
            const int* rout = (const int*)d_in[l.rb + 1];
            int P  = in_sizes[l.rb] / l.K;
            int KP = l.K * P;
            hipMemsetAsync(inv, 0xFF, (size_t)l.nout * l.K * sizeof(int), stream);
            inv_build_kernel<<<dim3((KP + TPB - 1) / TPB), dim3(TPB), 0, stream>>>(
                rin, rout, inv, KP, P, l.K, l.nin);
            prev_rb = l.rb;
        }

        unsigned blocks = (unsigned)((l.nout + l.tp - 1) / l.tp);
        int ys;
        if (l.K == 27) ys = (blocks >= 450) ? 1 : (blocks >= 150 ? 3 : 9);
        else           ys = (blocks >= 450) ? 1 : 3;
        int kpb = (l.K + ys - 1) / ys;

        if (ys > 1)   // atomic partials need zeroed output
            hipMemsetAsync(nxt, 0, (size_t)l.nout * l.co * sizeof(float), stream);

        dim3 grid(blocks, (unsigned)ys);
        #define LAUNCH(CI, CO, TP, K, DBF)                                        \
            do { if (ys == 1)                                                     \
                conv_kernel<CI, CO, TP, K, DBF, false><<<grid, 256, 0, stream>>>( \
                    cur, w, bn, inv, nxt, l.nout, kpb);                           \
            else                                                                  \
                conv_kernel<CI, CO, TP, K, DBF, true><<<grid, 256, 0, stream>>>(  \
                    cur, w, bn, inv, nxt, l.nout, kpb); } while (0)

        switch (i) {
        case 0:           LAUNCH(4,  16, 64, 27, true);  break;
        case 1:           LAUNCH(16, 16, 64, 27, true);  break;
        case 2:           LAUNCH(16, 32, 64, 27, true);  break;
        case 3: case 4:   LAUNCH(32, 32, 64, 27, true);  break;
        case 5:           LAUNCH(32, 64, 32, 27, true);  break;
        case 6: case 7:
        case 8: case 9:
        case 10:          LAUNCH(64, 64, 32, 27, true);  break;
        default:          LAUNCH(64, 128, 32, 3, false); break;  // DB LDS too big
        }
        #undef LAUNCH

        if (ys > 1) {
            long tot2 = (long)l.nout * l.co;
            bnrelu_kernel<<<dim3((unsigned)((tot2 + TPB - 1) / TPB)), dim3(TPB), 0, stream>>>(
                nxt, bn, tot2, l.co);
        }

        float* tmp = cur; cur = nxt; nxt = tmp;
    }

    // segment max -> d_out
    hipMemsetAsync(d_out, 0, (size_t)out_size * sizeof(float), stream);
    const int* bidx = (const int*)d_in[42];
    int nb = out_size / 128;
    segmax_kernel<<<dim3(128), dim3(256), 0, stream>>>(cur, bidx, (float*)d_out, n5, nb);
}

// Round 4
// 735.825 us; speedup vs baseline: 1.7762x; 1.7762x over previous
//
#include <hip/hip_runtime.h>

#define TPB 256
typedef unsigned short u16;
typedef __attribute__((ext_vector_type(8))) short short8v;
typedef __attribute__((ext_vector_type(4))) float f32x4;

__device__ __forceinline__ u16 f2bf(float x) {
    unsigned u = __float_as_uint(x);
    return (u16)((u + 0x7FFFu + ((u >> 16) & 1u)) >> 16);
}
__device__ __forceinline__ float bf2f(u16 h) {
    return __uint_as_float(((unsigned)h) << 16);
}

// ---- mean-VFE
__global__ void vfe_kernel(const float* __restrict__ voxels,
                           const int* __restrict__ nump,
                           float* __restrict__ x, int N) {
    int i = blockIdx.x * blockDim.x + threadIdx.x;
    if (i >= N * 4) return;
    int n = i >> 2, c = i & 3;
    const float* v = voxels + (long)n * 20 + c;
    float s = v[0] + v[4] + v[8] + v[12] + v[16];
    x[i] = s / fmaxf((float)nump[n], 1.0f);
}

// ---- invert rulebook: inv[out_row][k] = in_row (or -1)
__global__ void inv_build_kernel(const int* __restrict__ rb_in,
                                 const int* __restrict__ rb_out,
                                 int* __restrict__ inv,
                                 int KP, int P, int K, int n_in) {
    int t = blockIdx.x * blockDim.x + threadIdx.x;
    if (t >= KP) return;
    int ii = rb_in[t];
    if (ii == n_in) return;
    int k = t / P;
    inv[(long)rb_out[t] * K + k] = ii;
}

// ---- weight prep: fp32 [K][ci][co] -> bf16 hi/lo planes laid out [K][co][ci]
struct WPE { const float* w; u16* oh; u16* ol; int K, ci, co, total; };
struct WPA { WPE e[9]; };
__global__ void wprep_kernel(WPA a, int grand) {
    int t = blockIdx.x * blockDim.x + threadIdx.x;
    if (t >= grand) return;
    #pragma unroll
    for (int i = 0; i < 9; ++i) {
        if (t < a.e[i].total) {
            const WPE& E = a.e[i];
            int cc = E.ci * E.co;
            int k = t / cc, r = t % cc, c = r / E.co, o = r % E.co;
            float x = E.w[t];
            u16 h = f2bf(x);
            float lf = x - bf2f(h);
            long d = ((long)k * E.co + o) * E.ci + c;
            E.oh[d] = h; E.ol[d] = f2bf(lf);
            return;
        }
        t -= a.e[i].total;
    }
}

// ---- fp32 pipelined conv (layers 0-2), fused BN+ReLU; optional bf16-plane emit
template<int CI, int CO, int TP, int K, bool EMIT16>
__global__ __launch_bounds__(256)
void conv_kernel(const float* __restrict__ feats,
                 const float* __restrict__ w,    // [K][CI][CO]
                 const float* __restrict__ bn,
                 const int* __restrict__ inv,    // [n_out][K]
                 float* __restrict__ out,
                 u16* __restrict__ oh, u16* __restrict__ ol,
                 int n_out) {
    constexpr int OG  = CO / 4;
    constexpr int PTH = 256 / OG;
    constexpr int PT  = TP / PTH;
    constexpr int CIP = CI + 4;
    constexpr int W4  = CI * CO / 4;
    constexpr int WCH = (W4 + 255) / 256;
    constexpr int TR  = CI / 4;
    constexpr int RPS = 256 / TR;
    constexpr int ASW = (TP + RPS - 1) / RPS;

    __shared__ float sW[2][CI * CO];
    __shared__ float sA[2][TP * CIP];
    __shared__ int   sI[TP * K];

    const int brow = blockIdx.x * TP;
    const int t  = threadIdx.x;
    const int og = t % OG;
    const int pg = t / OG;

    {
        long base = (long)brow * K, lim = (long)n_out * K;
        for (int i = t; i < TP * K; i += 256)
            sI[i] = (base + i < lim) ? inv[base + i] : -1;
    }

    float4 wreg[WCH];
    float4 areg[ASW];

    auto load_regs = [&](int k) {
        const float4* src = (const float4*)(w + (long)k * CI * CO);
        #pragma unroll
        for (int c = 0; c < WCH; ++c) {
            int i = c * 256 + t;
            if (W4 >= 256 || i < W4) wreg[c] = src[i];
        }
        #pragma unroll
        for (int s = 0; s < ASW; ++s) {
            int r = s * RPS + t / TR;
            int c = (t % TR) * 4;
            float4 v = make_float4(0.f, 0.f, 0.f, 0.f);
            if (r < TP) {
                int idx = sI[r * K + k];
                if (idx >= 0) v = *(const float4*)(feats + (long)idx * CI + c);
            }
            areg[s] = v;
        }
    };
    auto store_lds = [&](int b) {
        #pragma unroll
        for (int c = 0; c < WCH; ++c) {
            int i = c * 256 + t;
            if (W4 >= 256 || i < W4) ((float4*)sW[b])[i] = wreg[c];
        }
        #pragma unroll
        for (int s = 0; s < ASW; ++s) {
            int r = s * RPS + t / TR;
            int c = (t % TR) * 4;
            if (r < TP) *(float4*)(&sA[b][r * CIP + c]) = areg[s];
        }
    };

    float acc[PT][4];
    #pragma unroll
    for (int i = 0; i < PT; ++i)
        acc[i][0] = acc[i][1] = acc[i][2] = acc[i][3] = 0.f;

    auto compute = [&](int b) {
        #pragma unroll 4
        for (int kk = 0; kk < CI; ++kk) {
            float4 wv = *(const float4*)(&sW[b][kk * CO + og * 4]);
            #pragma unroll
            for (int i = 0; i < PT; ++i) {
                float a = sA[b][(pg * PT + i) * CIP + kk];
                acc[i][0] = fmaf(a, wv.x, acc[i][0]);
                acc[i][1] = fmaf(a, wv.y, acc[i][1]);
                acc[i][2] = fmaf(a, wv.z, acc[i][2]);
                acc[i][3] = fmaf(a, wv.w, acc[i][3]);
            }
        }
    };

    __syncthreads();
    int cur = 0;
    load_regs(0);
    store_lds(0);
    for (int k = 0; k < K; ++k) {
        __syncthreads();
        if (k + 1 < K) load_regs(k + 1);
        compute(cur);
        if (k + 1 < K) store_lds(cur ^ 1);
        cur ^= 1;
    }

    float4 g = *(const float4*)(bn + og * 4);
    float4 b = *(const float4*)(bn + CO + og * 4);
    float4 m = *(const float4*)(bn + 2 * CO + og * 4);
    float4 v = *(const float4*)(bn + 3 * CO + og * 4);
    float s0 = rsqrtf(v.x + 1e-3f) * g.x;
    float s1 = rsqrtf(v.y + 1e-3f) * g.y;
    float s2 = rsqrtf(v.z + 1e-3f) * g.z;
    float s3 = rsqrtf(v.w + 1e-3f) * g.w;
    #pragma unroll
    for (int i = 0; i < PT; ++i) {
        int grow = brow + pg * PT + i;
        if (grow < n_out) {
            float o4[4];
            o4[0] = fmaxf(fmaf(acc[i][0] - m.x, s0, b.x), 0.f);
            o4[1] = fmaxf(fmaf(acc[i][1] - m.y, s1, b.y), 0.f);
            o4[2] = fmaxf(fmaf(acc[i][2] - m.z, s2, b.z), 0.f);
            o4[3] = fmaxf(fmaf(acc[i][3] - m.w, s3, b.w), 0.f);
            if (EMIT16) {
                long base = (long)grow * CO + og * 4;
                #pragma unroll
                for (int c = 0; c < 4; ++c) {
                    u16 h = f2bf(o4[c]);
                    oh[base + c] = h;
                    ol[base + c] = f2bf(o4[c] - bf2f(h));
                }
            } else {
                *(float4*)(out + (long)grow * CO + og * 4) =
                    make_float4(o4[0], o4[1], o4[2], o4[3]);
            }
        }
    }
}

// ---- MFMA sparse conv (bf16 hi/lo split, fp32 accumulate), TP=64, 4 waves.
// Writes fp32 partials to slab blockIdx.y (no atomics). A tile [row][ci],
// W prepped [K][co][ci]; frags: row/col=lane&15, k=8*(lane>>4); D per m89.
template<int CI, int CO, int K>
__global__ __launch_bounds__(256)
void mconv_kernel(const u16* __restrict__ fh, const u16* __restrict__ fl,
                  const u16* __restrict__ wh, const u16* __restrict__ wl,
                  const int* __restrict__ inv,
                  float* __restrict__ part, long slab_elems,
                  int n_out, int kpb) {
    constexpr int NT  = CO / 16;       // n tiles
    constexpr int KS  = CI / 32;       // mfma k-steps per tap
    constexpr int ACH = CI * 2 / 16;   // 16B chunks per A row per plane

    __shared__ __align__(16) u16 sAh[64 * CI];
    __shared__ __align__(16) u16 sAl[64 * CI];
    __shared__ __align__(16) u16 sBh[CO * CI];
    __shared__ __align__(16) u16 sBl[CO * CI];
    __shared__ int sI[64 * K];

    const int t = threadIdx.x;
    const int brow = blockIdx.x * 64;
    const int kbeg = blockIdx.y * kpb;
    const int kend = (kbeg + kpb < K) ? (kbeg + kpb) : K;

    {
        long base = (long)brow * K, lim = (long)n_out * K;
        for (int i = t; i < 64 * K; i += 256)
            sI[i] = (base + i < lim) ? inv[base + i] : -1;
    }

    f32x4 acc[NT];
    #pragma unroll
    for (int n = 0; n < NT; ++n) {
        acc[n][0] = 0.f; acc[n][1] = 0.f; acc[n][2] = 0.f; acc[n][3] = 0.f;
    }

    const int lane = t & 63, wid = t >> 6;
    const int frow = lane & 15;
    const int fko  = (lane >> 4) * 8;

    __syncthreads();
    for (int k = kbeg; k < kend; ++k) {
        __syncthreads();   // protect LDS until all waves finished prior compute
        // stage A (gathered rows, both planes)
        for (int i = t; i < 64 * ACH; i += 256) {
            int r = i / ACH, c = i % ACH;
            int idx = sI[r * K + k];
            float4 zh = make_float4(0.f, 0.f, 0.f, 0.f);
            float4 zl = zh;
            if (idx >= 0) {
                zh = *(const float4*)(fh + (long)idx * CI + c * 8);
                zl = *(const float4*)(fl + (long)idx * CI + c * 8);
            }
            *(float4*)(sAh + r * CI + c * 8) = zh;
            *(float4*)(sAl + r * CI + c * 8) = zl;
        }
        // stage B (contiguous prepped weights, both planes)
        {
            const float4* srcH = (const float4*)(wh + (long)k * CO * CI);
            const float4* srcL = (const float4*)(wl + (long)k * CO * CI);
            for (int i = t; i < CO * CI / 8; i += 256) {
                *(float4*)(sBh + i * 8) = srcH[i];
                *(float4*)(sBl + i * 8) = srcL[i];
            }
        }
        __syncthreads();
        const u16* aH = sAh + (wid * 16 + frow) * CI;
        const u16* aL = sAl + (wid * 16 + frow) * CI;
        #pragma unroll
        for (int ks = 0; ks < KS; ++ks) {
            short8v ah = *(const short8v*)(aH + ks * 32 + fko);
            short8v al = *(const short8v*)(aL + ks * 32 + fko);
            #pragma unroll
            for (int n = 0; n < NT; ++n) {
                const u16* bB = sBh + (n * 16 + frow) * CI + ks * 32 + fko;
                const u16* bL = sBl + (n * 16 + frow) * CI + ks * 32 + fko;
                short8v bh = *(const short8v*)bB;
                short8v bl = *(const short8v*)bL;
                acc[n] = __builtin_amdgcn_mfma_f32_16x16x32_bf16(ah, bh, acc[n], 0, 0, 0);
                acc[n] = __builtin_amdgcn_mfma_f32_16x16x32_bf16(ah, bl, acc[n], 0, 0, 0);
                acc[n] = __builtin_amdgcn_mfma_f32_16x16x32_bf16(al, bh, acc[n], 0, 0, 0);
            }
        }
    }

    float* dst = part + (long)blockIdx.y * slab_elems;
    int orow0 = brow + wid * 16 + (lane >> 4) * 4;
    int col = lane & 15;
    #pragma unroll
    for (int n = 0; n < NT; ++n) {
        #pragma unroll
        for (int j = 0; j < 4; ++j) {
            int r = orow0 + j;
            if (r < n_out) dst[(long)r * CO + n * 16 + col] = acc[n][j];
        }
    }
}

// ---- slab reduce + BN + ReLU (+ bf16 hi/lo emit OR fp32 out)
template<bool EMIT16>
__global__ void reduce_bnrelu_kernel(const float* __restrict__ part, long stride,
                                     int ys, const float* __restrict__ bn, int co,
                                     float* __restrict__ outf,
                                     u16* __restrict__ oh, u16* __restrict__ ol,
                                     long total) {
    long t = (long)blockIdx.x * blockDim.x + threadIdx.x;
    if (t >= total) return;
    float s = 0.f;
    for (int y = 0; y < ys; ++y) s += part[(long)y * stride + t];
    int o = (int)(t % co);
    float g = bn[o], b = bn[co + o], m = bn[2 * co + o], v = bn[3 * co + o];
    float yv = fmaxf((s - m) * rsqrtf(v + 1e-3f) * g + b, 0.f);
    if (EMIT16) {
        u16 h = f2bf(yv);
        oh[t] = h;
        ol[t] = f2bf(yv - bf2f(h));
    } else {
        outf[t] = yv;
    }
}

// ---- per-batch max pool: LDS accumulation, few global atomics
__global__ void segmax_kernel(const float* __restrict__ x,
                              const int* __restrict__ bidx,
                              float* __restrict__ out, int rows, int nb) {
    __shared__ float sM[8 * 128];
    for (int i = threadIdx.x; i < nb * 128; i += 256) sM[i] = 0.f;
    __syncthreads();
    int c = threadIdx.x & 127;
    int sub = threadIdx.x >> 7;
    for (int r = blockIdx.x * 2 + sub; r < rows; r += gridDim.x * 2) {
        float v = x[(long)r * 128 + c];
        int b = bidx[r];
        atomicMax((int*)&sM[b * 128 + c], __float_as_int(v));
    }
    __syncthreads();
    for (int i = threadIdx.x; i < nb * 128; i += 256)
        atomicMax((int*)out + i, __float_as_int(sM[i]));
}

extern "C" void kernel_launch(void* const* d_in, const int* in_sizes, int n_in,
                              void* d_out, int out_size, void* d_ws, size_t ws_size,
                              hipStream_t stream) {
    (void)n_in; (void)ws_size;
    const float* voxels = (const float*)d_in[24];
    const int*   nump   = (const int*)d_in[25];
    const int N  = in_sizes[25];
    const int n2 = in_sizes[30] / 27;
    const int n3 = in_sizes[34] / 27;
    const int n4 = in_sizes[38] / 27;
    const int n5 = in_sizes[42];

    struct L { int wi, rb, K, ci, co, nin, nout; };
    const L layers[12] = {
        {0,  26, 27,  4,  16, N,  N }, {1,  26, 27, 16,  16, N,  N },
        {2,  28, 27, 16,  32, N,  n2}, {3,  30, 27, 32,  32, n2, n2},
        {4,  30, 27, 32,  32, n2, n2}, {5,  32, 27, 32,  64, n2, n3},
        {6,  34, 27, 64,  64, n3, n3}, {7,  34, 27, 64,  64, n3, n3},
        {8,  36, 27, 64,  64, n3, n4}, {9,  38, 27, 64,  64, n4, n4},
        {10, 38, 27, 64,  64, n4, n4}, {11, 40,  3, 64, 128, n4, n5},
    };

    // ---- workspace carve-up
    size_t inv_elems = 0, feat_elems = (size_t)N * 4, wt_elems = 0;
    for (int i = 0; i < 12; ++i) {
        size_t ie = (size_t)layers[i].nout * layers[i].K;
        size_t fe = (size_t)layers[i].nout * layers[i].co;
        if (ie > inv_elems)  inv_elems  = ie;
        if (fe > feat_elems) feat_elems = fe;
        if (i >= 3) wt_elems += (size_t)layers[i].K * layers[i].ci * layers[i].co;
    }
    auto al = [](size_t x) { return (x + 255) & ~(size_t)255; };
    char* p = (char*)d_ws;
    int*   inv  = (int*)p;   p += al(inv_elems * 4);
    float* bufA = (float*)p; p += al(feat_elems * 4);
    float* bufB = (float*)p; p += al(feat_elems * 4);
    u16* ph[2]; u16* pl[2];
    ph[0] = (u16*)p; p += al(feat_elems * 2);
    pl[0] = (u16*)p; p += al(feat_elems * 2);
    ph[1] = (u16*)p; p += al(feat_elems * 2);
    pl[1] = (u16*)p; p += al(feat_elems * 2);
    u16* wth = (u16*)p; p += al(wt_elems * 2);
    u16* wtl = (u16*)p; p += al(wt_elems * 2);
    float* slab = (float*)p; p += al(3 * feat_elems * 4);

    // ---- VFE
    {
        long tot = (long)N * 4;
        vfe_kernel<<<dim3((unsigned)((tot + TPB - 1) / TPB)), dim3(TPB), 0, stream>>>(
            voxels, nump, bufA, N);
    }

    // ---- weight prep for MFMA layers (one kernel)
    size_t woff[9];
    {
        WPA wa;
        size_t off = 0;
        for (int i = 0; i < 9; ++i) {
            const L& l = layers[i + 3];
            woff[i] = off;
            wa.e[i].w  = (const float*)d_in[2 * l.wi];
            wa.e[i].oh = wth + off;
            wa.e[i].ol = wtl + off;
            wa.e[i].K = l.K; wa.e[i].ci = l.ci; wa.e[i].co = l.co;
            wa.e[i].total = l.K * l.ci * l.co;
            off += (size_t)wa.e[i].total;
        }
        int grand = (int)off;
        wprep_kernel<<<dim3((grand + TPB - 1) / TPB), dim3(TPB), 0, stream>>>(wa, grand);
    }

    int prev_rb = -1;
    auto build_inv = [&](const L& l) {
        if (l.rb == prev_rb) return;
        const int* rin  = (const int*)d_in[l.rb];
        const int* rout = (const int*)d_in[l.rb + 1];
        int P  = in_sizes[l.rb] / l.K;
        int KP = l.K * P;
        hipMemsetAsync(inv, 0xFF, (size_t)l.nout * l.K * sizeof(int), stream);
        inv_build_kernel<<<dim3((KP + TPB - 1) / TPB), dim3(TPB), 0, stream>>>(
            rin, rout, inv, KP, P, l.K, l.nin);
        prev_rb = l.rb;
    };

    // ---- fp32 layers 0-2
    {
        const L& l = layers[0];
        build_inv(l);
        conv_kernel<4, 16, 64, 27, false><<<dim3((l.nout + 63) / 64), 256, 0, stream>>>(
            bufA, (const float*)d_in[0], (const float*)d_in[1], inv,
            bufB, nullptr, nullptr, l.nout);
    }
    {
        const L& l = layers[1];
        build_inv(l);
        conv_kernel<16, 16, 64, 27, false><<<dim3((l.nout + 63) / 64), 256, 0, stream>>>(
            bufB, (const float*)d_in[2], (const float*)d_in[3], inv,
            bufA, nullptr, nullptr, l.nout);
    }
    {
        const L& l = layers[2];
        build_inv(l);
        conv_kernel<16, 32, 64, 27, true><<<dim3((l.nout + 63) / 64), 256, 0, stream>>>(
            bufA, (const float*)d_in[4], (const float*)d_in[5], inv,
            nullptr, ph[0], pl[0], l.nout);
    }

    // ---- MFMA layers 3-11
    int cset = 0;
    for (int i = 3; i < 12; ++i) {
        const L& l = layers[i];
        build_inv(l);
        unsigned blocks = (unsigned)((l.nout + 63) / 64);
        int ys = (blocks >= 400) ? 1 : (blocks >= 160 ? 2 : 3);
        int kpb = (l.K + ys - 1) / ys;
        long slab_elems = (long)l.nout * l.co;
        dim3 grid(blocks, (unsigned)ys);
        const u16* fh = ph[cset];
        const u16* fl = pl[cset];
        const u16* whp = wth + woff[i - 3];
        const u16* wlp = wtl + woff[i - 3];

        switch (i) {
        case 3: case 4:
            mconv_kernel<32, 32, 27><<<grid, 256, 0, stream>>>(
                fh, fl, whp, wlp, inv, slab, slab_elems, l.nout, kpb); break;
        case 5:
            mconv_kernel<32, 64, 27><<<grid, 256, 0, stream>>>(
                fh, fl, whp, wlp, inv, slab, slab_elems, l.nout, kpb); break;
        case 11:
            mconv_kernel<64, 128, 3><<<grid, 256, 0, stream>>>(
                fh, fl, whp, wlp, inv, slab, slab_elems, l.nout, kpb); break;
        default:
            mconv_kernel<64, 64, 27><<<grid, 256, 0, stream>>>(
                fh, fl, whp, wlp, inv, slab, slab_elems, l.nout, kpb); break;
        }

        long total = (long)l.nout * l.co;
        unsigned rblocks = (unsigned)((total + TPB - 1) / TPB);
        const float* bn = (const float*)d_in[2 * l.wi + 1];
        if (i < 11) {
            reduce_bnrelu_kernel<true><<<dim3(rblocks), dim3(TPB), 0, stream>>>(
                slab, slab_elems, ys, bn, l.co,
                nullptr, ph[cset ^ 1], pl[cset ^ 1], total);
            cset ^= 1;
        } else {
            reduce_bnrelu_kernel<false><<<dim3(rblocks), dim3(TPB), 0, stream>>>(
                slab, slab_elems, ys, bn, l.co, bufA, nullptr, nullptr, total);
        }
    }

    // ---- segment max
    hipMemsetAsync(d_out, 0, (size_t)out_size * sizeof(float), stream);
    const int* bidx = (const int*)d_in[42];
    int nb = out_size / 128;
    segmax_kernel<<<dim3(128), dim3(256), 0, stream>>>(bufA, bidx, (float*)d_out, n5, nb);
}